// Round 4
// baseline (610.588 us; speedup 1.0000x reference)
//
#include <hip/hip_runtime.h>

typedef __attribute__((ext_vector_type(8)))  short   short8;
typedef __attribute__((ext_vector_type(16))) float   floatx16;
typedef __attribute__((ext_vector_type(4)))  float   float4v;
typedef __attribute__((ext_vector_type(4)))  unsigned short ushort4v;

#define HH 8
#define NN 4096
#define DD 64
#define BT 128   // output tile edge
#define DH 32    // D processed per half
#define LDK 40   // padded LDS row stride (bf16 elems): 80B -> balanced banks

__device__ __forceinline__ unsigned short f2bf(float x) {
    unsigned int u = __float_as_uint(x);
    unsigned int r = u + 0x7fffu + ((u >> 16) & 1u);   // round-to-nearest-even
    return (unsigned short)(r >> 16);
}
__device__ __forceinline__ float bf2f(unsigned short b) {
    return __uint_as_float(((unsigned int)b) << 16);
}

__global__ __launch_bounds__(256, 3)
void hept_tile_kernel(const float* __restrict__ Q, const float* __restrict__ K,
                      float* __restrict__ out)
{
    __shared__ unsigned short sQh[BT][LDK];
    __shared__ unsigned short sQl[BT][LDK];
    __shared__ unsigned short sKh[BT][LDK];
    __shared__ unsigned short sKl[BT][LDK];
    __shared__ float q2s[BT];
    __shared__ float k2s[BT];

    const int tid  = threadIdx.x;
    const int lane = tid & 63;
    const int wave = tid >> 6;

    const int bid  = blockIdx.x;
    const int head = bid >> 10;        // 1024 tiles per head
    const int tile = bid & 1023;
    const int tm   = tile >> 5;        // 32 tiles per row dim
    const int tn   = tile & 31;

    const float* qbase = Q + ((size_t)head * NN + (size_t)tm * BT) * DD;
    const float* kbase = K + ((size_t)head * NN + (size_t)tn * BT) * DD;

    // wave -> 64x64 subtile
    const int wr   = (wave >> 1) * 64;
    const int wc   = (wave & 1) * 64;
    const int l31  = lane & 31;
    const int koff = (lane >> 5) * 8;  // k sub-offset inside a K=16 chunk

    floatx16 acc[2][2];
#pragma unroll
    for (int m = 0; m < 2; ++m)
#pragma unroll
        for (int n = 0; n < 2; ++n)
#pragma unroll
            for (int i = 0; i < 16; ++i) acc[m][n][i] = 0.f;

    const int srow = tid >> 3;  // 0..31
    const int sc4  = tid & 7;   // float4 column 0..7 (32 floats per half-row)

#pragma unroll
    for (int ph = 0; ph < 2; ++ph) {
        // ---------------- stage: fp32 -> bf16 hi/lo into LDS ----------------
#pragma unroll
        for (int it = 0; it < 4; ++it) {
            const int r = srow + it * 32;
            const float4v qv = *reinterpret_cast<const float4v*>(qbase + (size_t)r * DD + ph * DH + sc4 * 4);
            const float4v kv = *reinterpret_cast<const float4v*>(kbase + (size_t)r * DD + ph * DH + sc4 * 4);

            float qs = qv.x*qv.x + qv.y*qv.y + qv.z*qv.z + qv.w*qv.w;
            float ks = kv.x*kv.x + kv.y*kv.y + kv.z*kv.z + kv.w*kv.w;
            qs += __shfl_xor(qs, 1); qs += __shfl_xor(qs, 2); qs += __shfl_xor(qs, 4);
            ks += __shfl_xor(ks, 1); ks += __shfl_xor(ks, 2); ks += __shfl_xor(ks, 4);
            if (sc4 == 0) {
                if (ph == 0) { q2s[r] = qs;  k2s[r] = ks;  }
                else         { q2s[r] += qs; k2s[r] += ks; }
            }

            ushort4v qh4, ql4, kh4, kl4;
#pragma unroll
            for (int j = 0; j < 4; ++j) {
                const float x  = qv[j];
                const unsigned short xh = f2bf(x);
                qh4[j] = xh;
                ql4[j] = f2bf(x - bf2f(xh));
                const float y  = kv[j];
                const unsigned short yh = f2bf(y);
                kh4[j] = yh;
                kl4[j] = f2bf(y - bf2f(yh));
            }
            *reinterpret_cast<ushort4v*>(&sQh[r][sc4 * 4]) = qh4;
            *reinterpret_cast<ushort4v*>(&sQl[r][sc4 * 4]) = ql4;
            *reinterpret_cast<ushort4v*>(&sKh[r][sc4 * 4]) = kh4;
            *reinterpret_cast<ushort4v*>(&sKl[r][sc4 * 4]) = kl4;
        }
        __syncthreads();

        // ---------------- compute: 3 bf16 products, K=32 this half ----------------
#pragma unroll
        for (int c = 0; c < 2; ++c) {
            const int kk = c * 16 + koff;
            const short8 ah0 = *reinterpret_cast<const short8*>(&sQh[wr      + l31][kk]);
            const short8 ah1 = *reinterpret_cast<const short8*>(&sQh[wr + 32 + l31][kk]);
            const short8 bh0 = *reinterpret_cast<const short8*>(&sKh[wc      + l31][kk]);
            const short8 bh1 = *reinterpret_cast<const short8*>(&sKh[wc + 32 + l31][kk]);
            const short8 al0 = *reinterpret_cast<const short8*>(&sQl[wr      + l31][kk]);
            const short8 al1 = *reinterpret_cast<const short8*>(&sQl[wr + 32 + l31][kk]);
            const short8 bl0 = *reinterpret_cast<const short8*>(&sKl[wc      + l31][kk]);
            const short8 bl1 = *reinterpret_cast<const short8*>(&sKl[wc + 32 + l31][kk]);

            // qh . kh
            acc[0][0] = __builtin_amdgcn_mfma_f32_32x32x16_bf16(ah0, bh0, acc[0][0], 0, 0, 0);
            acc[0][1] = __builtin_amdgcn_mfma_f32_32x32x16_bf16(ah0, bh1, acc[0][1], 0, 0, 0);
            acc[1][0] = __builtin_amdgcn_mfma_f32_32x32x16_bf16(ah1, bh0, acc[1][0], 0, 0, 0);
            acc[1][1] = __builtin_amdgcn_mfma_f32_32x32x16_bf16(ah1, bh1, acc[1][1], 0, 0, 0);
            // qh . kl
            acc[0][0] = __builtin_amdgcn_mfma_f32_32x32x16_bf16(ah0, bl0, acc[0][0], 0, 0, 0);
            acc[0][1] = __builtin_amdgcn_mfma_f32_32x32x16_bf16(ah0, bl1, acc[0][1], 0, 0, 0);
            acc[1][0] = __builtin_amdgcn_mfma_f32_32x32x16_bf16(ah1, bl0, acc[1][0], 0, 0, 0);
            acc[1][1] = __builtin_amdgcn_mfma_f32_32x32x16_bf16(ah1, bl1, acc[1][1], 0, 0, 0);
            // ql . kh
            acc[0][0] = __builtin_amdgcn_mfma_f32_32x32x16_bf16(al0, bh0, acc[0][0], 0, 0, 0);
            acc[0][1] = __builtin_amdgcn_mfma_f32_32x32x16_bf16(al0, bh1, acc[0][1], 0, 0, 0);
            acc[1][0] = __builtin_amdgcn_mfma_f32_32x32x16_bf16(al1, bh0, acc[1][0], 0, 0, 0);
            acc[1][1] = __builtin_amdgcn_mfma_f32_32x32x16_bf16(al1, bh1, acc[1][1], 0, 0, 0);
        }
        if (ph == 0) __syncthreads();   // protect LDS before next half's staging
    }

    // ---------------- epilogue: dist^2 -> exp, full-line stores ----------------
    float* obase = out + ((size_t)head * NN + (size_t)tm * BT) * NN + (size_t)tn * BT;
#pragma unroll
    for (int m = 0; m < 2; ++m) {
#pragma unroll
        for (int n = 0; n < 2; ++n) {
#pragma unroll
            for (int reg = 0; reg < 16; ++reg) {
                const int rl = wr + m * 32 + (reg & 3) + 8 * (reg >> 2) + 4 * (lane >> 5);
                const int cl = wc + n * 32 + l31;
                float v = q2s[rl] + k2s[cl] - 2.0f * acc[m][n][reg];
                v = fmaxf(v, 0.0f);
                obase[(size_t)rl * NN + cl] = __expf(-0.5f * v);
            }
        }
    }
}

extern "C" void kernel_launch(void* const* d_in, const int* in_sizes, int n_in,
                              void* d_out, int out_size, void* d_ws, size_t ws_size,
                              hipStream_t stream) {
    const float* q = (const float*)d_in[0];
    const float* k = (const float*)d_in[1];
    float* out = (float*)d_out;
    // 8 heads * (4096/128)^2 tiles = 8192 workgroups
    hept_tile_kernel<<<dim3(8192), dim3(256), 0, stream>>>(q, k, out);
}

// Round 6
// 556.190 us; speedup vs baseline: 1.0978x; 1.0978x over previous
//
#include <hip/hip_runtime.h>

typedef __attribute__((ext_vector_type(8)))  short          short8;
typedef __attribute__((ext_vector_type(8)))  unsigned short ushort8;
typedef __attribute__((ext_vector_type(16))) float          floatx16;

#define HH 8
#define NN 4096
#define DD 64
#define BT 128   // output tile edge
#define DH 32    // D processed per half
#define LDK 40   // padded LDS row stride (bf16 elems): 80B -> balanced banks

__device__ __forceinline__ unsigned short f2bf(float x) {
    unsigned int u = __float_as_uint(x);
    unsigned int r = u + 0x7fffu + ((u >> 16) & 1u);   // round-to-nearest-even
    return (unsigned short)(r >> 16);
}
__device__ __forceinline__ float bf2f(unsigned short b) {
    return __uint_as_float(((unsigned int)b) << 16);
}

// ---------------------------------------------------------------------------
// Prep: fp32 -> (hi,lo) bf16 decomposition + exact fp32 row norms, done ONCE
// (the round-4 kernel redid this 32x per row inside every tile block).
// One wave per row of 64 elements.
// ---------------------------------------------------------------------------
__global__ __launch_bounds__(256)
void hept_prep_kernel(const float* __restrict__ Q, const float* __restrict__ K,
                      unsigned short* __restrict__ qh, unsigned short* __restrict__ ql,
                      unsigned short* __restrict__ kh, unsigned short* __restrict__ kl,
                      float* __restrict__ q2, float* __restrict__ k2)
{
    const int lane = threadIdx.x & 63;
    const int row  = blockIdx.x * 4 + (threadIdx.x >> 6);  // 0..65535
    const int isK  = row >> 15;                             // rows 32768+ are K
    const int r    = row & 32767;

    const float* src = isK ? K : Q;
    const float x = src[(size_t)r * DD + lane];

    const unsigned short h  = f2bf(x);
    const unsigned short lo = f2bf(x - bf2f(h));

    float s = x * x;
    s += __shfl_xor(s, 1);  s += __shfl_xor(s, 2);  s += __shfl_xor(s, 4);
    s += __shfl_xor(s, 8);  s += __shfl_xor(s, 16); s += __shfl_xor(s, 32);

    unsigned short* hp = isK ? kh : qh;
    unsigned short* lp = isK ? kl : ql;
    hp[(size_t)r * DD + lane] = h;
    lp[(size_t)r * DD + lane] = lo;
    if (lane == 0) (isK ? k2 : q2)[r] = s;
}

// ---------------------------------------------------------------------------
// Main: 128x128 output tile per block; staging is pure b128 load -> b128
// ds_write (no conversion VALU, small live range -> no spill risk).
// MFMA layout / epilogue identical to the version verified at absmax 9e-13.
// ---------------------------------------------------------------------------
__global__ __launch_bounds__(256, 3)
void hept_main_kernel(const unsigned short* __restrict__ qh_g, const unsigned short* __restrict__ ql_g,
                      const unsigned short* __restrict__ kh_g, const unsigned short* __restrict__ kl_g,
                      const float* __restrict__ q2_g, const float* __restrict__ k2_g,
                      float* __restrict__ out)
{
    __shared__ unsigned short sQh[BT][LDK];
    __shared__ unsigned short sQl[BT][LDK];
    __shared__ unsigned short sKh[BT][LDK];
    __shared__ unsigned short sKl[BT][LDK];
    __shared__ float q2s[BT];
    __shared__ float k2s[BT];

    const int tid  = threadIdx.x;
    const int lane = tid & 63;
    const int wave = tid >> 6;

    const int bid  = blockIdx.x;
    const int head = bid >> 10;        // 1024 tiles per head
    const int tile = bid & 1023;
    const int tm   = tile >> 5;
    const int tn   = tile & 31;

    const size_t qoff = ((size_t)head * NN + (size_t)tm * BT) * DD;
    const size_t koff_g = ((size_t)head * NN + (size_t)tn * BT) * DD;
    const unsigned short* tqh = qh_g + qoff;
    const unsigned short* tql = ql_g + qoff;
    const unsigned short* tkh = kh_g + koff_g;
    const unsigned short* tkl = kl_g + koff_g;

    // row norms straight into LDS (written before first barrier, read in epilogue)
    if (tid < BT) q2s[tid]      = q2_g[head * NN + tm * BT + tid];
    else          k2s[tid - BT] = k2_g[head * NN + tn * BT + (tid - BT)];

    // wave -> 64x64 subtile
    const int wr   = (wave >> 1) * 64;
    const int wc   = (wave & 1) * 64;
    const int l31  = lane & 31;
    const int koff = (lane >> 5) * 8;

    floatx16 acc[2][2];
#pragma unroll
    for (int m = 0; m < 2; ++m)
#pragma unroll
        for (int n = 0; n < 2; ++n)
#pragma unroll
            for (int i = 0; i < 16; ++i) acc[m][n][i] = 0.f;

    const int prow = tid >> 2;        // 0..63
    const int pcol = (tid & 3) * 8;   // 0,8,16,24 (ushort8 granularity)

#pragma unroll
    for (int ph = 0; ph < 2; ++ph) {
        // ---- stage: straight copy global bf16 -> LDS (b128 both sides) ----
#define STG(SRC, DST)                                                                     \
        {                                                                                 \
            ushort8 v0 = *reinterpret_cast<const ushort8*>(SRC + (size_t)prow * DD        + ph * DH + pcol); \
            ushort8 v1 = *reinterpret_cast<const ushort8*>(SRC + (size_t)(prow + 64) * DD + ph * DH + pcol); \
            *reinterpret_cast<ushort8*>(&DST[prow][pcol])      = v0;                      \
            *reinterpret_cast<ushort8*>(&DST[prow + 64][pcol]) = v1;                      \
        }
        STG(tqh, sQh)
        STG(tql, sQl)
        STG(tkh, sKh)
        STG(tkl, sKl)
#undef STG
        __syncthreads();

        // ---- compute: 3 bf16 products (hh, hl, lh), K=32 this half ----
#pragma unroll
        for (int c = 0; c < 2; ++c) {
            const int kk = c * 16 + koff;
            const short8 ah0 = *reinterpret_cast<const short8*>(&sQh[wr      + l31][kk]);
            const short8 ah1 = *reinterpret_cast<const short8*>(&sQh[wr + 32 + l31][kk]);
            const short8 bh0 = *reinterpret_cast<const short8*>(&sKh[wc      + l31][kk]);
            const short8 bh1 = *reinterpret_cast<const short8*>(&sKh[wc + 32 + l31][kk]);
            const short8 al0 = *reinterpret_cast<const short8*>(&sQl[wr      + l31][kk]);
            const short8 al1 = *reinterpret_cast<const short8*>(&sQl[wr + 32 + l31][kk]);
            const short8 bl0 = *reinterpret_cast<const short8*>(&sKl[wc      + l31][kk]);
            const short8 bl1 = *reinterpret_cast<const short8*>(&sKl[wc + 32 + l31][kk]);

            acc[0][0] = __builtin_amdgcn_mfma_f32_32x32x16_bf16(ah0, bh0, acc[0][0], 0, 0, 0);
            acc[0][1] = __builtin_amdgcn_mfma_f32_32x32x16_bf16(ah0, bh1, acc[0][1], 0, 0, 0);
            acc[1][0] = __builtin_amdgcn_mfma_f32_32x32x16_bf16(ah1, bh0, acc[1][0], 0, 0, 0);
            acc[1][1] = __builtin_amdgcn_mfma_f32_32x32x16_bf16(ah1, bh1, acc[1][1], 0, 0, 0);

            acc[0][0] = __builtin_amdgcn_mfma_f32_32x32x16_bf16(ah0, bl0, acc[0][0], 0, 0, 0);
            acc[0][1] = __builtin_amdgcn_mfma_f32_32x32x16_bf16(ah0, bl1, acc[0][1], 0, 0, 0);
            acc[1][0] = __builtin_amdgcn_mfma_f32_32x32x16_bf16(ah1, bl0, acc[1][0], 0, 0, 0);
            acc[1][1] = __builtin_amdgcn_mfma_f32_32x32x16_bf16(ah1, bl1, acc[1][1], 0, 0, 0);

            acc[0][0] = __builtin_amdgcn_mfma_f32_32x32x16_bf16(al0, bh0, acc[0][0], 0, 0, 0);
            acc[0][1] = __builtin_amdgcn_mfma_f32_32x32x16_bf16(al0, bh1, acc[0][1], 0, 0, 0);
            acc[1][0] = __builtin_amdgcn_mfma_f32_32x32x16_bf16(al1, bh0, acc[1][0], 0, 0, 0);
            acc[1][1] = __builtin_amdgcn_mfma_f32_32x32x16_bf16(al1, bh1, acc[1][1], 0, 0, 0);
        }
        if (ph == 0) __syncthreads();
    }

    // ---- epilogue: dist^2 -> exp, full-line stores ----
    float* obase = out + ((size_t)head * NN + (size_t)tm * BT) * NN + (size_t)tn * BT;
#pragma unroll
    for (int m = 0; m < 2; ++m) {
#pragma unroll
        for (int n = 0; n < 2; ++n) {
#pragma unroll
            for (int reg = 0; reg < 16; ++reg) {
                const int rl = wr + m * 32 + (reg & 3) + 8 * (reg >> 2) + 4 * (lane >> 5);
                const int cl = wc + n * 32 + l31;
                float v = q2s[rl] + k2s[cl] - 2.0f * acc[m][n][reg];
                v = fmaxf(v, 0.0f);
                obase[(size_t)rl * NN + cl] = __expf(-0.5f * v);
            }
        }
    }
}

extern "C" void kernel_launch(void* const* d_in, const int* in_sizes, int n_in,
                              void* d_out, int out_size, void* d_ws, size_t ws_size,
                              hipStream_t stream) {
    const float* q = (const float*)d_in[0];
    const float* k = (const float*)d_in[1];
    float* out = (float*)d_out;

    // ws layout (bytes): qh[4MiB] ql[4MiB] kh[4MiB] kl[4MiB] q2[128KiB] k2[128KiB]
    char* ws = (char*)d_ws;
    const size_t ARR = (size_t)HH * NN * DD * sizeof(unsigned short); // 4 MiB
    unsigned short* qh = (unsigned short*)(ws);
    unsigned short* ql = (unsigned short*)(ws + ARR);
    unsigned short* kh = (unsigned short*)(ws + 2 * ARR);
    unsigned short* kl = (unsigned short*)(ws + 3 * ARR);
    float* q2 = (float*)(ws + 4 * ARR);
    float* k2 = (float*)(ws + 4 * ARR + (size_t)HH * NN * sizeof(float));

    // 65536 rows (Q then K), one wave each, 4 waves per block
    hept_prep_kernel<<<dim3(16384), dim3(256), 0, stream>>>(q, k, qh, ql, kh, kl, q2, k2);
    // 8 heads * 32 * 32 tiles
    hept_main_kernel<<<dim3(8192), dim3(256), 0, stream>>>(qh, ql, kh, kl, q2, k2, out);
}